// Round 5
// baseline (1894.077 us; speedup 1.0000x reference)
//
#include <hip/hip_runtime.h>
#include <hip/hip_bf16.h>

using bf16 = __hip_bfloat16;
typedef short short8 __attribute__((ext_vector_type(8)));
typedef short short4v __attribute__((ext_vector_type(4)));
typedef float f32x16 __attribute__((ext_vector_type(16)));

#define NT 196416

__device__ __forceinline__ void gload16(const bf16* g, char* l) {
  __builtin_amdgcn_global_load_lds((const __attribute__((address_space(1))) void*)g,
                                   (__attribute__((address_space(3))) void*)l, 16, 0, 0);
}

template <int N> __device__ __forceinline__ void vmw() {
  asm volatile("s_waitcnt vmcnt(%0)" ::"n"(N) : "memory");
}

// ---------- weight prep: HWIO f32 -> staged slot order bf16 ----------
// slot (16B) = ((((nb*16 + k)*2 + c)*TAPS + t)*128 + col); val[j]=w[t][k*16+c*8+j][nb*128+col]
__global__ void prep_w(const float* __restrict__ src, bf16* __restrict__ dst,
                       int Cout, int NB, int TAPS, int layers, long sstride) {
  const long spl = (long)NB * 16 * 2 * TAPS * 128;
  const long total = spl * layers;
  for (long s = blockIdx.x * (long)blockDim.x + threadIdx.x; s < total;
       s += (long)gridDim.x * blockDim.x) {
    long layer = s / spl;
    long r = s - layer * spl;
    int col = (int)(r & 127);
    long q = r >> 7;
    int t = (int)(q % TAPS); q /= TAPS;
    int c = (int)(q & 1); q >>= 1;
    int k = (int)(q & 15);
    int nb = (int)(q >> 4);
    int co = nb * 128 + col;
    short8 v = {};
    if (co < Cout) {
      const float* p = src + layer * sstride + ((long)(t * 256 + k * 16 + c * 8)) * Cout + co;
#pragma unroll
      for (int j = 0; j < 8; ++j) {
        union { bf16 b; short s16; } u;
        u.b = __float2bfloat16(p[(long)j * Cout]);
        v[j] = u.s16;
      }
    }
    *(short8*)(dst + s * 8) = v;
  }
}

// ---------- halo zero for nbuf padded buffers ----------
__global__ void halo_kernel(bf16* __restrict__ base, long BS, int W, int nbuf) {
  const int P = 2 * (W + 2) + 2 * W;
  const long n = (long)nbuf * 2 * P * 256;
  for (long t = blockIdx.x * (long)blockDim.x + threadIdx.x; t < n;
       t += (long)gridDim.x * blockDim.x) {
    int ch = (int)(t & 255);
    long q = t >> 8;
    int pix = (int)(q % P);
    int q2 = (int)(q / P);
    int img = q2 & 1;
    int buf = q2 >> 1;
    int row, col;
    if (pix < W + 2) { row = 0; col = pix; }
    else if (pix < 2 * (W + 2)) { row = W + 1; col = pix - (W + 2); }
    else { int e = pix - 2 * (W + 2); row = 1 + (e >> 1); col = (e & 1) ? W + 1 : 0; }
    bf16* p = base + buf * BS + ((long)(img * (W + 2) + row) * (W + 2) + col) * 256 + ch;
    union { bf16 b; short s16; } u; u.s16 = 0;
    *p = u.b;
  }
}

// ---------- cast f32 feats -> bf16 padded interior ----------
__global__ void cast_feat_kernel(const float* __restrict__ in, bf16* __restrict__ out,
                                 int wshift) {
  const int W = 1 << wshift;
  const long n4 = 2L * W * W * 64;
  for (long t = blockIdx.x * (long)blockDim.x + threadIdx.x; t < n4;
       t += (long)gridDim.x * blockDim.x) {
    int c4 = (int)(t & 63);
    long q = t >> 6;
    int w = (int)(q & (W - 1));
    long q2 = q >> wshift;
    int h = (int)(q2 & (W - 1));
    int b = (int)(q2 >> wshift);
    const float4 f = *(const float4*)(in + (((long)(b * W + h) * W + w) * 256 + c4 * 4));
    short4v v;
    union { bf16 b16; short s16; } u;
    u.b16 = __float2bfloat16(f.x); v[0] = u.s16;
    u.b16 = __float2bfloat16(f.y); v[1] = u.s16;
    u.b16 = __float2bfloat16(f.z); v[2] = u.s16;
    u.b16 = __float2bfloat16(f.w); v[3] = u.s16;
    *(short4v*)(out + (((long)(b * (W + 2) + h + 1) * (W + 2) + w + 1) * 256 + c4 * 4)) = v;
  }
}

// ---------- conv implicit GEMM (macro-inlined stage/compute: NO lambdas, acc must
// stay in VGPRs — lambda ref-capture in the previous revision spilled acc to
// scratch: VGPR=112 < 128-reg accumulator, 1.65 GB scratch writes/dispatch) ----------
#define STAGE_M(cc, ldsb)                                                        \
  do {                                                                           \
    _Pragma("unroll") for (int i_ = 0; i_ < UPW; ++i_) {                         \
      const int u_ = wid + NW * i_;                                              \
      if (u_ < UA) {                                                             \
        const int cg_ = (u_ >= PG) ? 1 : 0;                                      \
        const int pu_ = (u_ - cg_ * PG) * 64;                                    \
        gload16(gA + ((long)(pu_ + lane) * 256 + cg_ * 8 + (cc) * 16),           \
                (ldsb) + (cg_ * PPA + pu_) * 16);                                \
      } else {                                                                   \
        const int s0_ = (u_ - UA) * 64;                                          \
        gload16(gB + (long)(cc) * (TAPS * 2048) + (s0_ + lane) * 8,              \
                (ldsb) + ABYTES + s0_ * 16);                                     \
      }                                                                          \
    }                                                                            \
  } while (0)

#define COMPUTE_M(ldsb)                                                          \
  do {                                                                           \
    _Pragma("unroll") for (int t_ = 0; t_ < TAPS; ++t_) {                        \
      const int TOFF_ = (TAPS == 9) ? (((t_ / 3) * (W + 2) + (t_ % 3)) * 16)     \
                                    : ((W + 3) * 16);                            \
      const short8 bf0_ = *(const short8*)((ldsb) + b16[0] + t_ * 2048);         \
      const short8 bf1_ = *(const short8*)((ldsb) + b16[1] + t_ * 2048);         \
      _Pragma("unroll") for (int mf_ = 0; mf_ < MFR; ++mf_) {                    \
        const short8 af_ = *(const short8*)((ldsb) + a16[mf_] + TOFF_);          \
        acc[mf_][0] =                                                            \
            __builtin_amdgcn_mfma_f32_32x32x16_bf16(af_, bf0_, acc[mf_][0], 0, 0, 0); \
        acc[mf_][1] =                                                            \
            __builtin_amdgcn_mfma_f32_32x32x16_bf16(af_, bf1_, acc[mf_][1], 0, 0, 0); \
      }                                                                          \
    }                                                                            \
  } while (0)

template <int WSH, int WM, int WN, int MFR, int TAPS, int EPI, int DBUF>
__global__ __launch_bounds__(WM * WN * 64, 2) void conv_t(
    const bf16* __restrict__ inA, const bf16* __restrict__ inB,
    const bf16* __restrict__ wpA, const bf16* __restrict__ wpB,
    const float* __restrict__ biasA, const float* __restrict__ biasB,
    bf16* __restrict__ outA, bf16* __restrict__ outB,
    const int* __restrict__ labels, const float* __restrict__ tdel,
    int abase, float* __restrict__ lout, int Cout, int nbHalf) {
  constexpr int W = 1 << WSH;
  constexpr int NW = WM * WN;
  constexpr int BM = WM * MFR * 32;
  constexpr int R = BM >> WSH;
  constexpr int PP = (R + 2) * (W + 2);
  constexpr int PPA0 = ((PP + 63) / 64) * 64;
  constexpr int PPA = (NW == 4 && (PPA0 % 128)) ? PPA0 + 64 : PPA0;
  constexpr int PG = PPA / 64;
  constexpr int UA = PPA / 32;
  constexpr int UB = TAPS * 4;
  constexpr int U = UA + UB;
  static_assert(U % NW == 0, "unit padding");
  constexpr int UPW = U / NW;
  constexpr int ABYTES = 2 * PPA * 16;
  constexpr int BUFB = ABYTES + TAPS * 4096;

  __shared__ __align__(16) char smem[BUFB * (DBUF ? 2 : 1)];

  const int tid = threadIdx.x;
  const int lane = tid & 63;
  const int wid = tid >> 6;
  const int wm = wid / WN;
  const int wn = wid % WN;
  const int l31 = lane & 31;
  const int lh = lane >> 5;

  const int yb = blockIdx.y;
  const int half = (yb >= nbHalf) ? 1 : 0;
  const int nb = yb - half * nbHalf;
  const int n0 = nb * 128;
  const int rb = blockIdx.x;
  const int img = blockIdx.z;

  const bf16* in = half ? inB : inA;
  const bf16* wp = half ? wpB : wpA;
  const float* bias = half ? biasB : biasA;
  bf16* outp = half ? outB : outA;

  const bf16* gA = in + (long)(img * (W + 2) + rb * R) * ((W + 2) * 256);
  const bf16* gB = wp + (long)nb * (TAPS * 32768);

  int a16[MFR];
#pragma unroll
  for (int mf = 0; mf < MFR; ++mf) {
    const int mrow = wm * (MFR * 32) + mf * 32 + l31;
    const int pb = (mrow >> WSH) * (W + 2) + (mrow & (W - 1));
    a16[mf] = (lh * PPA + pb) * 16;
  }
  int b16[2];
#pragma unroll
  for (int nf = 0; nf < 2; ++nf)
    b16[nf] = ABYTES + (lh * (TAPS * 128) + wn * 64 + nf * 32 + l31) * 16;

  f32x16 acc[MFR][2];
#pragma unroll
  for (int mf = 0; mf < MFR; ++mf) {
    acc[mf][0] = (f32x16)(0.f);
    acc[mf][1] = (f32x16)(0.f);
  }

  if constexpr (DBUF) {
    char* bb0 = smem;
    char* bb1 = smem + BUFB;
    STAGE_M(0, bb0);
#pragma unroll 1
    for (int i = 0; i < 8; ++i) {
      STAGE_M(2 * i + 1, bb1);
      vmw<UPW>();
      __builtin_amdgcn_s_barrier();
      COMPUTE_M(bb0);
      __builtin_amdgcn_s_barrier();
      if (i < 7) {
        STAGE_M(2 * i + 2, bb0);
        vmw<UPW>();
      } else {
        vmw<0>();
      }
      __builtin_amdgcn_s_barrier();
      COMPUTE_M(bb1);
      __builtin_amdgcn_s_barrier();
    }
  } else {
#pragma unroll 1
    for (int cc = 0; cc < 16; ++cc) {
      __syncthreads();
      STAGE_M(cc, smem);
      __syncthreads();
      COMPUTE_M(smem);
    }
  }

  if constexpr (EPI == 0) {
#pragma unroll
    for (int nf = 0; nf < 2; ++nf) {
      const int co = n0 + wn * 64 + nf * 32 + l31;
      const float bv = bias[co];
#pragma unroll
      for (int mf = 0; mf < MFR; ++mf) {
#pragma unroll
        for (int r = 0; r < 16; ++r) {
          const int mrow = wm * (MFR * 32) + mf * 32 + (r & 3) + 8 * (r >> 2) + 4 * lh;
          const int rr = rb * BM + mrow;
          const int h = rr >> WSH;
          const int w = rr & (W - 1);
          float v = acc[mf][nf][r] + bv;
          if (TAPS == 9) v = fmaxf(v, 0.f);
          outp[((long)(img * (W + 2) + h + 1) * (W + 2) + (w + 1)) * 256 + co] =
              __float2bfloat16(v);
        }
      }
    }
  } else {
    // stage labels (and deltas) for this block's rows into LDS
    __syncthreads();
    int* lsh = (int*)smem;
    float* dsh = (float*)(smem + BM * 9 * 4);
    const long lbase = (long)img * NT + abase + (long)rb * BM * 9;
    for (int i = tid; i < BM * 9; i += NW * 64) lsh[i] = labels[lbase + i];
    if constexpr (EPI == 2) {
      for (int i = tid; i < BM * 9 * 4; i += NW * 64) dsh[i] = tdel[lbase * 4 + i];
    }
    __syncthreads();

    float lsum = 0.f;
#pragma unroll
    for (int nf = 0; nf < 2; ++nf) {
      const int co = n0 + wn * 64 + nf * 32 + l31;
      if (co < Cout) {
        const float bv = bias[co];
        int aidx, sub;
        if constexpr (EPI == 1) { aidx = co / 80; sub = co - aidx * 80; }
        else { aidx = co >> 2; sub = co & 3; }
#pragma unroll
        for (int mf = 0; mf < MFR; ++mf) {
#pragma unroll
          for (int r = 0; r < 16; ++r) {
            const int mrow = wm * (MFR * 32) + mf * 32 + (r & 3) + 8 * (r >> 2) + 4 * lh;
            const int label = lsh[mrow * 9 + aidx];
            const float z = acc[mf][nf][r] + bv;
            if constexpr (EPI == 1) {
              if (label >= 0) {
                const float tt = (label == sub) ? 1.f : 0.f;
                const float ce = fmaxf(z, 0.f) - z * tt + log1pf(expf(-fabsf(z)));
                const float p = 1.f / (1.f + expf(-z));
                const float pt = p * tt + (1.f - p) * (1.f - tt);
                const float om = 1.f - pt;
                lsum += (0.25f * tt + 0.75f * (1.f - tt)) * ce * om * om;
              }
            } else {
              if (label >= 0 && label != 80) {
                lsum += fabsf(z - dsh[(mrow * 9 + aidx) * 4 + sub]);
              }
            }
          }
        }
      }
    }
#pragma unroll
    for (int off = 32; off > 0; off >>= 1) lsum += __shfl_down(lsum, off, 64);
    __syncthreads();
    float* red = (float*)smem;
    if (lane == 0) red[wid] = lsum;
    __syncthreads();
    if (tid == 0) {
      float s = 0.f;
      for (int i = 0; i < NW; ++i) s += red[i];
      atomicAdd(lout, s * 0.01f);
    }
  }
}

// ---------------- host ----------------
static inline int igrid(long n, int cap) {
  long g = (n + 255) / 256;
  return (int)(g > cap ? cap : g);
}

struct LvlArgs {
  bf16* bufs; long BS;
  const bf16 *wip, *wcls, *wbox, *wsc, *wpred;
  const float *ipb, *ccb, *csb, *bcb, *bpb;
  const int* labels; const float* tdel;
  int abase; float* out;
};

template <int WSH, int WM, int WN, int MFR, int TDB>
static void run_level(const LvlArgs& A, bool merged, hipStream_t s) {
  constexpr int W = 1 << WSH;
  constexpr int BM = WM * MFR * 32;
  const int m = (W * W) / BM;
  dim3 blk(WM * WN * 64);
  if (merged) {
    bf16* xb = A.bufs;
    bf16* c0 = A.bufs + A.BS;
    bf16* c1 = A.bufs + 2 * A.BS;
    bf16* d0 = A.bufs + 3 * A.BS;
    bf16* d1 = A.bufs + 4 * A.BS;
    conv_t<WSH, WM, WN, MFR, 1, 0, 1><<<dim3(m, 2, 2), blk, 0, s>>>(
        c1, c1, A.wip, A.wip, A.ipb, A.ipb, xb, xb, nullptr, nullptr, 0, nullptr, 256, 2);
    const bf16* ci = xb; const bf16* bi = xb;
    bf16* co_[4] = {c0, c1, c0, c1};
    bf16* bo_[4] = {d0, d1, d0, d1};
    for (int j = 0; j < 4; ++j) {
      conv_t<WSH, WM, WN, MFR, 9, 0, TDB><<<dim3(m, 4, 2), blk, 0, s>>>(
          ci, bi, A.wcls + (long)j * 589824, A.wbox + (long)j * 589824,
          A.ccb + j * 256, A.bcb + j * 256, co_[j], bo_[j],
          nullptr, nullptr, 0, nullptr, 256, 2);
      ci = co_[j]; bi = bo_[j];
    }
    conv_t<WSH, WM, WN, MFR, 9, 1, TDB><<<dim3(m, 6, 2), blk, 0, s>>>(
        ci, ci, A.wsc, A.wsc, A.csb, A.csb, nullptr, nullptr,
        A.labels, nullptr, A.abase, A.out + 0, 720, 6);
    conv_t<WSH, WM, WN, MFR, 9, 2, TDB><<<dim3(m, 1, 2), blk, 0, s>>>(
        bi, bi, A.wpred, A.wpred, A.bpb, A.bpb, nullptr, nullptr,
        A.labels, A.tdel, A.abase, A.out + 1, 36, 1);
  } else {
    bf16* xb = A.bufs;
    bf16* t0 = A.bufs + A.BS;
    bf16* t1 = A.bufs + 2 * A.BS;
    conv_t<WSH, WM, WN, MFR, 1, 0, 1><<<dim3(m, 2, 2), blk, 0, s>>>(
        t0, t0, A.wip, A.wip, A.ipb, A.ipb, xb, xb, nullptr, nullptr, 0, nullptr, 256, 2);
    for (int br = 0; br < 2; ++br) {
      const bf16* wt = br ? A.wbox : A.wcls;
      const float* bb = br ? A.bcb : A.ccb;
      const bf16* ci = xb;
      bf16* oo[4] = {t1, t0, t1, t0};
      for (int j = 0; j < 4; ++j) {
        conv_t<WSH, WM, WN, MFR, 9, 0, TDB><<<dim3(m, 2, 2), blk, 0, s>>>(
            ci, ci, wt + (long)j * 589824, wt + (long)j * 589824, bb + j * 256, bb + j * 256,
            oo[j], oo[j], nullptr, nullptr, 0, nullptr, 256, 2);
        ci = oo[j];
      }
      if (br == 0)
        conv_t<WSH, WM, WN, MFR, 9, 1, TDB><<<dim3(m, 6, 2), blk, 0, s>>>(
            t0, t0, A.wsc, A.wsc, A.csb, A.csb, nullptr, nullptr,
            A.labels, nullptr, A.abase, A.out + 0, 720, 6);
      else
        conv_t<WSH, WM, WN, MFR, 9, 2, TDB><<<dim3(m, 1, 2), blk, 0, s>>>(
            t0, t0, A.wpred, A.wpred, A.bpb, A.bpb, nullptr, nullptr,
            A.labels, A.tdel, A.abase, A.out + 1, 36, 1);
    }
  }
}

extern "C" void kernel_launch(void* const* d_in, const int* in_sizes, int n_in,
                              void* d_out, int out_size, void* d_ws, size_t ws_size,
                              hipStream_t stream) {
  const float* feat_in[5] = {(const float*)d_in[0], (const float*)d_in[1],
                             (const float*)d_in[2], (const float*)d_in[3],
                             (const float*)d_in[4]};
  const int* labels = (const int*)d_in[5];
  const float* adeltas = (const float*)d_in[6];
  const float* ipw = (const float*)d_in[7];
  const float* ipb = (const float*)d_in[8];
  const float* ccw = (const float*)d_in[9];
  const float* ccb = (const float*)d_in[10];
  const float* csw = (const float*)d_in[11];
  const float* csb = (const float*)d_in[12];
  const float* bcw = (const float*)d_in[13];
  const float* bcb = (const float*)d_in[14];
  const float* bpw = (const float*)d_in[15];
  const float* bpb = (const float*)d_in[16];
  float* out = (float*)d_out;

  const long BUFE = 2L * 130 * 130 * 256;
  const long GAP = 65536;
  const long BS = BUFE + GAP;
  const long WELEMS = 327680 + 2359296 + 2359296 + 1769472 + 294912;
  const bool merged = ws_size >= (size_t)((5 * BS + WELEMS) * 2);
  const int nbuf = merged ? 5 : 3;

  bf16* ws = (bf16*)d_ws;
  bf16* wp_ip = ws + nbuf * BS;
  bf16* wp_cls = wp_ip + 327680;
  bf16* wp_box = wp_cls + 2359296;
  bf16* wp_sc = wp_box + 2359296;
  bf16* wp_pred = wp_sc + 1769472;

  hipMemsetAsync(d_out, 0, 2 * sizeof(float), stream);

  prep_w<<<igrid(5L * 8192, 1024), 256, 0, stream>>>(ipw, wp_ip, 256, 2, 1, 5, 65536);
  prep_w<<<igrid(4L * 73728, 1024), 256, 0, stream>>>(ccw, wp_cls, 256, 2, 9, 4, 589824);
  prep_w<<<igrid(4L * 73728, 1024), 256, 0, stream>>>(bcw, wp_box, 256, 2, 9, 4, 589824);
  prep_w<<<igrid(221184L, 1024), 256, 0, stream>>>(csw, wp_sc, 720, 6, 9, 1, 0);
  prep_w<<<igrid(36864L, 1024), 256, 0, stream>>>(bpw, wp_pred, 36, 1, 9, 1, 0);

  static const int LS[5] = {7, 6, 5, 4, 3};
  static const int AB[5] = {0, 147456, 184320, 193536, 195840};

  bf16* featsBuf = ws + (merged ? 2 : 1) * BS;

  for (int l = 0; l < 5; ++l) {
    const int W = 1 << LS[l];
    halo_kernel<<<igrid((long)nbuf * 2 * (4 * W + 4) * 256, 2048), 256, 0, stream>>>(
        ws, BS, W, nbuf);
    cast_feat_kernel<<<igrid(2L * W * W * 64, 2048), 256, 0, stream>>>(
        feat_in[l], featsBuf, LS[l]);

    LvlArgs A;
    A.bufs = ws; A.BS = BS;
    A.wip = wp_ip + (long)l * 65536; A.ipb = ipb + l * 256;
    A.wcls = wp_cls; A.wbox = wp_box; A.wsc = wp_sc; A.wpred = wp_pred;
    A.ccb = ccb; A.csb = csb; A.bcb = bcb; A.bpb = bpb;
    A.labels = labels; A.tdel = adeltas; A.abase = AB[l]; A.out = out;

    switch (l) {
      case 0: run_level<7, 2, 2, 4, 0>(A, merged, stream); break;
      case 1: run_level<6, 2, 2, 2, 1>(A, merged, stream); break;
      case 2: run_level<5, 1, 2, 2, 1>(A, merged, stream); break;
      case 3: run_level<4, 1, 2, 2, 1>(A, merged, stream); break;
      case 4: run_level<3, 1, 2, 2, 1>(A, merged, stream); break;
    }
  }
}

// Round 6
// 1807.652 us; speedup vs baseline: 1.0478x; 1.0478x over previous
//
#include <hip/hip_runtime.h>
#include <hip/hip_bf16.h>

using bf16 = __hip_bfloat16;
typedef short short8 __attribute__((ext_vector_type(8)));
typedef short short4v __attribute__((ext_vector_type(4)));
typedef float f32x16 __attribute__((ext_vector_type(16)));

#define NT 196416

__device__ __forceinline__ void gload16(const bf16* g, char* l) {
  __builtin_amdgcn_global_load_lds((const __attribute__((address_space(1))) void*)g,
                                   (__attribute__((address_space(3))) void*)l, 16, 0, 0);
}

template <int N> __device__ __forceinline__ void vmw() {
  asm volatile("s_waitcnt vmcnt(%0)" ::"n"(N) : "memory");
}

// ---------- weight prep: HWIO f32 -> staged slot order bf16 ----------
__global__ void prep_w(const float* __restrict__ src, bf16* __restrict__ dst,
                       int Cout, int NB, int TAPS, int layers, long sstride) {
  const long spl = (long)NB * 16 * 2 * TAPS * 128;
  const long total = spl * layers;
  for (long s = blockIdx.x * (long)blockDim.x + threadIdx.x; s < total;
       s += (long)gridDim.x * blockDim.x) {
    long layer = s / spl;
    long r = s - layer * spl;
    int col = (int)(r & 127);
    long q = r >> 7;
    int t = (int)(q % TAPS); q /= TAPS;
    int c = (int)(q & 1); q >>= 1;
    int k = (int)(q & 15);
    int nb = (int)(q >> 4);
    int co = nb * 128 + col;
    short8 v = {};
    if (co < Cout) {
      const float* p = src + layer * sstride + ((long)(t * 256 + k * 16 + c * 8)) * Cout + co;
#pragma unroll
      for (int j = 0; j < 8; ++j) {
        union { bf16 b; short s16; } u;
        u.b = __float2bfloat16(p[(long)j * Cout]);
        v[j] = u.s16;
      }
    }
    *(short8*)(dst + s * 8) = v;
  }
}

// ---------- halo zero ----------
__global__ void halo_kernel(bf16* __restrict__ base, long BS, int W, int nbuf) {
  const int P = 2 * (W + 2) + 2 * W;
  const long n = (long)nbuf * 2 * P * 256;
  for (long t = blockIdx.x * (long)blockDim.x + threadIdx.x; t < n;
       t += (long)gridDim.x * blockDim.x) {
    int ch = (int)(t & 255);
    long q = t >> 8;
    int pix = (int)(q % P);
    int q2 = (int)(q / P);
    int img = q2 & 1;
    int buf = q2 >> 1;
    int row, col;
    if (pix < W + 2) { row = 0; col = pix; }
    else if (pix < 2 * (W + 2)) { row = W + 1; col = pix - (W + 2); }
    else { int e = pix - 2 * (W + 2); row = 1 + (e >> 1); col = (e & 1) ? W + 1 : 0; }
    bf16* p = base + buf * BS + ((long)(img * (W + 2) + row) * (W + 2) + col) * 256 + ch;
    union { bf16 b; short s16; } u; u.s16 = 0;
    *p = u.b;
  }
}

// ---------- cast f32 feats -> bf16 padded interior ----------
__global__ void cast_feat_kernel(const float* __restrict__ in, bf16* __restrict__ out,
                                 int wshift) {
  const int W = 1 << wshift;
  const long n4 = 2L * W * W * 64;
  for (long t = blockIdx.x * (long)blockDim.x + threadIdx.x; t < n4;
       t += (long)gridDim.x * blockDim.x) {
    int c4 = (int)(t & 63);
    long q = t >> 6;
    int w = (int)(q & (W - 1));
    long q2 = q >> wshift;
    int h = (int)(q2 & (W - 1));
    int b = (int)(q2 >> wshift);
    const float4 f = *(const float4*)(in + (((long)(b * W + h) * W + w) * 256 + c4 * 4));
    short4v v;
    union { bf16 b16; short s16; } u;
    u.b16 = __float2bfloat16(f.x); v[0] = u.s16;
    u.b16 = __float2bfloat16(f.y); v[1] = u.s16;
    u.b16 = __float2bfloat16(f.z); v[2] = u.s16;
    u.b16 = __float2bfloat16(f.w); v[3] = u.s16;
    *(short4v*)(out + (((long)(b * (W + 2) + h + 1) * (W + 2) + w + 1) * 256 + c4 * 4)) = v;
  }
}

// ---------- conv implicit GEMM ----------
// NAMED accumulators (no arrays): rounds 3-5 spilled the f32x16 acc[MFR][2]
// aggregate to scratch (VGPR=108 < 128-reg acc; 1.67 GB HBM writes/dispatch of
// pure spill traffic at 4 TB/s). Named scalars are trivially SROA-promotable.

#define MFMA_(a, b, c) __builtin_amdgcn_mfma_f32_32x32x16_bf16((a), (b), (c), 0, 0, 0)

#define STAGE_M(cc, ldsb)                                                        \
  do {                                                                           \
    _Pragma("unroll") for (int i_ = 0; i_ < UPW; ++i_) {                         \
      const int u_ = wid + NW * i_;                                              \
      if (u_ < UA) {                                                             \
        const int cg_ = (u_ >= PG) ? 1 : 0;                                      \
        const int pu_ = (u_ - cg_ * PG) * 64;                                    \
        gload16(gA + ((long)(pu_ + lane) * 256 + cg_ * 8 + (cc) * 16),           \
                (ldsb) + (cg_ * PPA + pu_) * 16);                                \
      } else {                                                                   \
        const int s0_ = (u_ - UA) * 64;                                          \
        gload16(gB + (long)(cc) * (TAPS * 2048) + (s0_ + lane) * 8,              \
                (ldsb) + ABYTES + s0_ * 16);                                     \
      }                                                                          \
    }                                                                            \
  } while (0)

#define COMPUTE_M(ldsb)                                                          \
  do {                                                                           \
    _Pragma("unroll") for (int t_ = 0; t_ < TAPS; ++t_) {                        \
      const int TOFF_ = (TAPS == 9) ? ((((t_) / 3) * (W + 2) + ((t_) % 3)) * 16) \
                                    : ((W + 3) * 16);                            \
      const short8 b0_ = *(const short8*)((ldsb) + b16_0 + (t_) * 2048);         \
      const short8 b1_ = *(const short8*)((ldsb) + b16_1 + (t_) * 2048);         \
      {                                                                          \
        const short8 a_ = *(const short8*)((ldsb) + a16_0 + TOFF_);              \
        c0a = MFMA_(a_, b0_, c0a); c0b = MFMA_(a_, b1_, c0b);                    \
      }                                                                          \
      {                                                                          \
        const short8 a_ = *(const short8*)((ldsb) + a16_1 + TOFF_);              \
        c1a = MFMA_(a_, b0_, c1a); c1b = MFMA_(a_, b1_, c1b);                    \
      }                                                                          \
      if constexpr (MFR > 2) {                                                   \
        {                                                                        \
          const short8 a_ = *(const short8*)((ldsb) + a16_2 + TOFF_);            \
          c2a = MFMA_(a_, b0_, c2a); c2b = MFMA_(a_, b1_, c2b);                  \
        }                                                                        \
        {                                                                        \
          const short8 a_ = *(const short8*)((ldsb) + a16_3 + TOFF_);            \
          c3a = MFMA_(a_, b0_, c3a); c3b = MFMA_(a_, b1_, c3b);                  \
        }                                                                        \
      }                                                                          \
    }                                                                            \
  } while (0)

#define AOFF_(mf_)                                                               \
  ((lh * PPA + (((wm * (MFR * 32) + (mf_) * 32 + l31) >> WSH) * (W + 2)) +       \
    ((wm * (MFR * 32) + (mf_) * 32 + l31) & (W - 1))) * 16)

#define STORE_PAIR(mf_, accv, nf_)                                               \
  do {                                                                           \
    const int co_ = n0 + wn * 64 + (nf_) * 32 + l31;                             \
    const float bv_ = bias[co_];                                                 \
    _Pragma("unroll") for (int r_ = 0; r_ < 16; ++r_) {                          \
      const int mrow_ =                                                          \
          wm * (MFR * 32) + (mf_) * 32 + (r_ & 3) + 8 * (r_ >> 2) + 4 * lh;      \
      const int rr_ = rb * BM + mrow_;                                           \
      const int h_ = rr_ >> WSH;                                                 \
      const int w_ = rr_ & (W - 1);                                              \
      float v_ = accv[r_] + bv_;                                                 \
      if (TAPS == 9) v_ = fmaxf(v_, 0.f);                                        \
      outp[((long)(img * (W + 2) + h_ + 1) * (W + 2) + (w_ + 1)) * 256 + co_] =  \
          __float2bfloat16(v_);                                                  \
    }                                                                            \
  } while (0)

#define LOSS_PAIR(mf_, accv, nf_)                                                \
  do {                                                                           \
    const int co_ = n0 + wn * 64 + (nf_) * 32 + l31;                             \
    if (co_ < Cout) {                                                            \
      const float bv_ = bias[co_];                                               \
      int aidx_, sub_;                                                           \
      if constexpr (EPI == 1) { aidx_ = co_ / 80; sub_ = co_ - aidx_ * 80; }     \
      else { aidx_ = co_ >> 2; sub_ = co_ & 3; }                                 \
      _Pragma("unroll") for (int r_ = 0; r_ < 16; ++r_) {                        \
        const int mrow_ =                                                        \
            wm * (MFR * 32) + (mf_) * 32 + (r_ & 3) + 8 * (r_ >> 2) + 4 * lh;    \
        const int label_ = lsh[mrow_ * 9 + aidx_];                               \
        const float z_ = accv[r_] + bv_;                                         \
        if constexpr (EPI == 1) {                                                \
          if (label_ >= 0) {                                                     \
            const float tt_ = (label_ == sub_) ? 1.f : 0.f;                      \
            const float ce_ = fmaxf(z_, 0.f) - z_ * tt_ + log1pf(expf(-fabsf(z_))); \
            const float p_ = 1.f / (1.f + expf(-z_));                            \
            const float pt_ = p_ * tt_ + (1.f - p_) * (1.f - tt_);               \
            const float om_ = 1.f - pt_;                                         \
            lsum += (0.25f * tt_ + 0.75f * (1.f - tt_)) * ce_ * om_ * om_;       \
          }                                                                      \
        } else {                                                                 \
          if (label_ >= 0 && label_ != 80) {                                     \
            lsum += fabsf(z_ - dsh[(mrow_ * 9 + aidx_) * 4 + sub_]);             \
          }                                                                      \
        }                                                                        \
      }                                                                          \
    }                                                                            \
  } while (0)

template <int WSH, int WM, int WN, int MFR, int TAPS, int EPI, int DBUF>
__global__ __launch_bounds__(WM * WN * 64) void conv_t(
    const bf16* __restrict__ inA, const bf16* __restrict__ inB,
    const bf16* __restrict__ wpA, const bf16* __restrict__ wpB,
    const float* __restrict__ biasA, const float* __restrict__ biasB,
    bf16* __restrict__ outA, bf16* __restrict__ outB,
    const int* __restrict__ labels, const float* __restrict__ tdel,
    int abase, float* __restrict__ lout, int Cout, int nbHalf) {
  constexpr int W = 1 << WSH;
  constexpr int NW = WM * WN;
  constexpr int BM = WM * MFR * 32;
  constexpr int R = BM >> WSH;
  constexpr int PP = (R + 2) * (W + 2);
  constexpr int PPA0 = ((PP + 63) / 64) * 64;
  constexpr int PPA = (NW == 4 && (PPA0 % 128)) ? PPA0 + 64 : PPA0;
  constexpr int PG = PPA / 64;
  constexpr int UA = PPA / 32;
  constexpr int UB = TAPS * 4;
  constexpr int U = UA + UB;
  static_assert(U % NW == 0, "unit padding");
  constexpr int UPW = U / NW;
  constexpr int ABYTES = 2 * PPA * 16;
  constexpr int BUFB = ABYTES + TAPS * 4096;

  __shared__ __align__(16) char smem[BUFB * (DBUF ? 2 : 1)];

  const int tid = threadIdx.x;
  const int lane = tid & 63;
  const int wid = tid >> 6;
  const int wm = wid / WN;
  const int wn = wid % WN;
  const int l31 = lane & 31;
  const int lh = lane >> 5;

  const int yb = blockIdx.y;
  const int half = (yb >= nbHalf) ? 1 : 0;
  const int nb = yb - half * nbHalf;
  const int n0 = nb * 128;
  const int rb = blockIdx.x;
  const int img = blockIdx.z;

  const bf16* in = half ? inB : inA;
  const bf16* wp = half ? wpB : wpA;
  const float* bias = half ? biasB : biasA;
  bf16* outp = half ? outB : outA;

  const bf16* gA = in + (long)(img * (W + 2) + rb * R) * ((W + 2) * 256);
  const bf16* gB = wp + (long)nb * (TAPS * 32768);

  const int a16_0 = AOFF_(0);
  const int a16_1 = AOFF_(1);
  const int a16_2 = (MFR > 2) ? AOFF_(2) : 0;
  const int a16_3 = (MFR > 2) ? AOFF_(3) : 0;
  const int b16_0 = ABYTES + (lh * (TAPS * 128) + wn * 64 + l31) * 16;
  const int b16_1 = ABYTES + (lh * (TAPS * 128) + wn * 64 + 32 + l31) * 16;

  f32x16 c0a = (f32x16)(0.f), c0b = (f32x16)(0.f);
  f32x16 c1a = (f32x16)(0.f), c1b = (f32x16)(0.f);
  f32x16 c2a = (f32x16)(0.f), c2b = (f32x16)(0.f);
  f32x16 c3a = (f32x16)(0.f), c3b = (f32x16)(0.f);

  if constexpr (DBUF) {
    char* bb0 = smem;
    char* bb1 = smem + BUFB;
    STAGE_M(0, bb0);
#pragma unroll 1
    for (int i = 0; i < 8; ++i) {
      STAGE_M(2 * i + 1, bb1);
      vmw<UPW>();
      __builtin_amdgcn_s_barrier();
      COMPUTE_M(bb0);
      __builtin_amdgcn_s_barrier();
      if (i < 7) {
        STAGE_M(2 * i + 2, bb0);
        vmw<UPW>();
      } else {
        vmw<0>();
      }
      __builtin_amdgcn_s_barrier();
      COMPUTE_M(bb1);
      __builtin_amdgcn_s_barrier();
    }
  } else {
#pragma unroll 1
    for (int cc = 0; cc < 16; ++cc) {
      __syncthreads();
      STAGE_M(cc, smem);
      __syncthreads();
      COMPUTE_M(smem);
    }
  }

  if constexpr (EPI == 0) {
    STORE_PAIR(0, c0a, 0); STORE_PAIR(0, c0b, 1);
    STORE_PAIR(1, c1a, 0); STORE_PAIR(1, c1b, 1);
    if constexpr (MFR > 2) {
      STORE_PAIR(2, c2a, 0); STORE_PAIR(2, c2b, 1);
      STORE_PAIR(3, c3a, 0); STORE_PAIR(3, c3b, 1);
    }
  } else {
    __syncthreads();
    int* lsh = (int*)smem;
    float* dsh = (float*)(smem + BM * 9 * 4);
    const long lbase = (long)img * NT + abase + (long)rb * BM * 9;
    for (int i = tid; i < BM * 9; i += NW * 64) lsh[i] = labels[lbase + i];
    if constexpr (EPI == 2) {
      for (int i = tid; i < BM * 9 * 4; i += NW * 64) dsh[i] = tdel[lbase * 4 + i];
    }
    __syncthreads();

    float lsum = 0.f;
    LOSS_PAIR(0, c0a, 0); LOSS_PAIR(0, c0b, 1);
    LOSS_PAIR(1, c1a, 0); LOSS_PAIR(1, c1b, 1);
    if constexpr (MFR > 2) {
      LOSS_PAIR(2, c2a, 0); LOSS_PAIR(2, c2b, 1);
      LOSS_PAIR(3, c3a, 0); LOSS_PAIR(3, c3b, 1);
    }
#pragma unroll
    for (int off = 32; off > 0; off >>= 1) lsum += __shfl_down(lsum, off, 64);
    __syncthreads();
    float* red = (float*)smem;
    if (lane == 0) red[wid] = lsum;
    __syncthreads();
    if (tid == 0) {
      float s = 0.f;
      for (int i = 0; i < NW; ++i) s += red[i];
      atomicAdd(lout, s * 0.01f);
    }
  }
}

// ---------------- host ----------------
static inline int igrid(long n, int cap) {
  long g = (n + 255) / 256;
  return (int)(g > cap ? cap : g);
}

struct LvlArgs {
  bf16* bufs; long BS;
  const bf16 *wip, *wcls, *wbox, *wsc, *wpred;
  const float *ipb, *ccb, *csb, *bcb, *bpb;
  const int* labels; const float* tdel;
  int abase; float* out;
};

template <int WSH, int WM, int WN, int MFR, int TDB>
static void run_level(const LvlArgs& A, bool merged, hipStream_t s) {
  constexpr int W = 1 << WSH;
  constexpr int BM = WM * MFR * 32;
  const int m = (W * W) / BM;
  dim3 blk(WM * WN * 64);
  if (merged) {
    bf16* xb = A.bufs;
    bf16* c0 = A.bufs + A.BS;
    bf16* c1 = A.bufs + 2 * A.BS;
    bf16* d0 = A.bufs + 3 * A.BS;
    bf16* d1 = A.bufs + 4 * A.BS;
    conv_t<WSH, WM, WN, MFR, 1, 0, 1><<<dim3(m, 2, 2), blk, 0, s>>>(
        c1, c1, A.wip, A.wip, A.ipb, A.ipb, xb, xb, nullptr, nullptr, 0, nullptr, 256, 2);
    const bf16* ci = xb; const bf16* bi = xb;
    bf16* co_[4] = {c0, c1, c0, c1};
    bf16* bo_[4] = {d0, d1, d0, d1};
    for (int j = 0; j < 4; ++j) {
      conv_t<WSH, WM, WN, MFR, 9, 0, TDB><<<dim3(m, 4, 2), blk, 0, s>>>(
          ci, bi, A.wcls + (long)j * 589824, A.wbox + (long)j * 589824,
          A.ccb + j * 256, A.bcb + j * 256, co_[j], bo_[j],
          nullptr, nullptr, 0, nullptr, 256, 2);
      ci = co_[j]; bi = bo_[j];
    }
    conv_t<WSH, WM, WN, MFR, 9, 1, TDB><<<dim3(m, 6, 2), blk, 0, s>>>(
        ci, ci, A.wsc, A.wsc, A.csb, A.csb, nullptr, nullptr,
        A.labels, nullptr, A.abase, A.out + 0, 720, 6);
    conv_t<WSH, WM, WN, MFR, 9, 2, TDB><<<dim3(m, 1, 2), blk, 0, s>>>(
        bi, bi, A.wpred, A.wpred, A.bpb, A.bpb, nullptr, nullptr,
        A.labels, A.tdel, A.abase, A.out + 1, 36, 1);
  } else {
    bf16* xb = A.bufs;
    bf16* t0 = A.bufs + A.BS;
    bf16* t1 = A.bufs + 2 * A.BS;
    conv_t<WSH, WM, WN, MFR, 1, 0, 1><<<dim3(m, 2, 2), blk, 0, s>>>(
        t0, t0, A.wip, A.wip, A.ipb, A.ipb, xb, xb, nullptr, nullptr, 0, nullptr, 256, 2);
    for (int br = 0; br < 2; ++br) {
      const bf16* wt = br ? A.wbox : A.wcls;
      const float* bb = br ? A.bcb : A.ccb;
      const bf16* ci = xb;
      bf16* oo[4] = {t1, t0, t1, t0};
      for (int j = 0; j < 4; ++j) {
        conv_t<WSH, WM, WN, MFR, 9, 0, TDB><<<dim3(m, 2, 2), blk, 0, s>>>(
            ci, ci, wt + (long)j * 589824, wt + (long)j * 589824, bb + j * 256, bb + j * 256,
            oo[j], oo[j], nullptr, nullptr, 0, nullptr, 256, 2);
        ci = oo[j];
      }
      if (br == 0)
        conv_t<WSH, WM, WN, MFR, 9, 1, TDB><<<dim3(m, 6, 2), blk, 0, s>>>(
            t0, t0, A.wsc, A.wsc, A.csb, A.csb, nullptr, nullptr,
            A.labels, nullptr, A.abase, A.out + 0, 720, 6);
      else
        conv_t<WSH, WM, WN, MFR, 9, 2, TDB><<<dim3(m, 1, 2), blk, 0, s>>>(
            t0, t0, A.wpred, A.wpred, A.bpb, A.bpb, nullptr, nullptr,
            A.labels, A.tdel, A.abase, A.out + 1, 36, 1);
    }
  }
}

extern "C" void kernel_launch(void* const* d_in, const int* in_sizes, int n_in,
                              void* d_out, int out_size, void* d_ws, size_t ws_size,
                              hipStream_t stream) {
  const float* feat_in[5] = {(const float*)d_in[0], (const float*)d_in[1],
                             (const float*)d_in[2], (const float*)d_in[3],
                             (const float*)d_in[4]};
  const int* labels = (const int*)d_in[5];
  const float* adeltas = (const float*)d_in[6];
  const float* ipw = (const float*)d_in[7];
  const float* ipb = (const float*)d_in[8];
  const float* ccw = (const float*)d_in[9];
  const float* ccb = (const float*)d_in[10];
  const float* csw = (const float*)d_in[11];
  const float* csb = (const float*)d_in[12];
  const float* bcw = (const float*)d_in[13];
  const float* bcb = (const float*)d_in[14];
  const float* bpw = (const float*)d_in[15];
  const float* bpb = (const float*)d_in[16];
  float* out = (float*)d_out;

  const long BUFE = 2L * 130 * 130 * 256;
  const long GAP = 65536;
  const long BS = BUFE + GAP;
  const long WELEMS = 327680 + 2359296 + 2359296 + 1769472 + 294912;
  const bool merged = ws_size >= (size_t)((5 * BS + WELEMS) * 2);
  const int nbuf = merged ? 5 : 3;

  bf16* ws = (bf16*)d_ws;
  bf16* wp_ip = ws + nbuf * BS;
  bf16* wp_cls = wp_ip + 327680;
  bf16* wp_box = wp_cls + 2359296;
  bf16* wp_sc = wp_box + 2359296;
  bf16* wp_pred = wp_sc + 1769472;

  hipMemsetAsync(d_out, 0, 2 * sizeof(float), stream);

  prep_w<<<igrid(5L * 8192, 1024), 256, 0, stream>>>(ipw, wp_ip, 256, 2, 1, 5, 65536);
  prep_w<<<igrid(4L * 73728, 1024), 256, 0, stream>>>(ccw, wp_cls, 256, 2, 9, 4, 589824);
  prep_w<<<igrid(4L * 73728, 1024), 256, 0, stream>>>(bcw, wp_box, 256, 2, 9, 4, 589824);
  prep_w<<<igrid(221184L, 1024), 256, 0, stream>>>(csw, wp_sc, 720, 6, 9, 1, 0);
  prep_w<<<igrid(36864L, 1024), 256, 0, stream>>>(bpw, wp_pred, 36, 1, 9, 1, 0);

  static const int LS[5] = {7, 6, 5, 4, 3};
  static const int AB[5] = {0, 147456, 184320, 193536, 195840};

  bf16* featsBuf = ws + (merged ? 2 : 1) * BS;

  for (int l = 0; l < 5; ++l) {
    const int W = 1 << LS[l];
    halo_kernel<<<igrid((long)nbuf * 2 * (4 * W + 4) * 256, 2048), 256, 0, stream>>>(
        ws, BS, W, nbuf);
    cast_feat_kernel<<<igrid(2L * W * W * 64, 2048), 256, 0, stream>>>(
        feat_in[l], featsBuf, LS[l]);

    LvlArgs A;
    A.bufs = ws; A.BS = BS;
    A.wip = wp_ip + (long)l * 65536; A.ipb = ipb + l * 256;
    A.wcls = wp_cls; A.wbox = wp_box; A.wsc = wp_sc; A.wpred = wp_pred;
    A.ccb = ccb; A.csb = csb; A.bcb = bcb; A.bpb = bpb;
    A.labels = labels; A.tdel = adeltas; A.abase = AB[l]; A.out = out;

    switch (l) {
      case 0: run_level<7, 2, 2, 4, 0>(A, merged, stream); break;
      case 1: run_level<6, 2, 2, 2, 1>(A, merged, stream); break;
      case 2: run_level<5, 1, 2, 2, 1>(A, merged, stream); break;
      case 3: run_level<4, 1, 2, 2, 1>(A, merged, stream); break;
      case 4: run_level<3, 1, 2, 2, 1>(A, merged, stream); break;
    }
  }
}

// Round 7
// 1519.728 us; speedup vs baseline: 1.2463x; 1.1895x over previous
//
#include <hip/hip_runtime.h>
#include <hip/hip_bf16.h>

using bf16 = __hip_bfloat16;
typedef short short8 __attribute__((ext_vector_type(8)));
typedef short short4v __attribute__((ext_vector_type(4)));
typedef float f32x16 __attribute__((ext_vector_type(16)));

#define NT 196416

__device__ __forceinline__ void gload16(const bf16* g, char* l) {
  __builtin_amdgcn_global_load_lds((const __attribute__((address_space(1))) void*)g,
                                   (__attribute__((address_space(3))) void*)l, 16, 0, 0);
}

template <int N> __device__ __forceinline__ void vmw() {
  asm volatile("s_waitcnt vmcnt(%0)" ::"n"(N) : "memory");
}

constexpr int pick_ppa(int PP, int UB, int NW) {
  int p = ((PP + 63) / 64) * 64;
  while (((p / 32 + UB) % NW) != 0) p += 64;
  return p;
}

// ---------- weight prep: HWIO f32 -> staged slot order bf16 (unchanged) ----------
__global__ void prep_w(const float* __restrict__ src, bf16* __restrict__ dst,
                       int Cout, int NB, int TAPS, int layers, long sstride) {
  const long spl = (long)NB * 16 * 2 * TAPS * 128;
  const long total = spl * layers;
  for (long s = blockIdx.x * (long)blockDim.x + threadIdx.x; s < total;
       s += (long)gridDim.x * blockDim.x) {
    long layer = s / spl;
    long r = s - layer * spl;
    int col = (int)(r & 127);
    long q = r >> 7;
    int t = (int)(q % TAPS); q /= TAPS;
    int c = (int)(q & 1); q >>= 1;
    int k = (int)(q & 15);
    int nb = (int)(q >> 4);
    int co = nb * 128 + col;
    short8 v = {};
    if (co < Cout) {
      const float* p = src + layer * sstride + ((long)(t * 256 + k * 16 + c * 8)) * Cout + co;
#pragma unroll
      for (int j = 0; j < 8; ++j) {
        union { bf16 b; short s16; } u;
        u.b = __float2bfloat16(p[(long)j * Cout]);
        v[j] = u.s16;
      }
    }
    *(short8*)(dst + s * 8) = v;
  }
}

// ---------- halo zero (channel-blocked layout: [img][32 planes][pix][8]) ----------
__global__ void halo_kernel(bf16* __restrict__ base, long BS, int W, int nbuf) {
  const int P = 2 * (W + 2) + 2 * W;
  const long PLSZ8 = (long)(W + 2) * (W + 2) * 8;
  const long n = (long)nbuf * 2 * P * 256;
  for (long t = blockIdx.x * (long)blockDim.x + threadIdx.x; t < n;
       t += (long)gridDim.x * blockDim.x) {
    int ch = (int)(t & 255);
    long q = t >> 8;
    int pix = (int)(q % P);
    int q2 = (int)(q / P);
    int img = q2 & 1;
    int buf = q2 >> 1;
    int row, col;
    if (pix < W + 2) { row = 0; col = pix; }
    else if (pix < 2 * (W + 2)) { row = W + 1; col = pix - (W + 2); }
    else { int e = pix - 2 * (W + 2); row = 1 + (e >> 1); col = (e & 1) ? W + 1 : 0; }
    bf16* p = base + buf * BS + ((long)(img * 32 + (ch >> 3))) * PLSZ8 +
              ((long)row * (W + 2) + col) * 8 + (ch & 7);
    union { bf16 b; short s16; } u; u.s16 = 0;
    *p = u.b;
  }
}

// ---------- cast f32 feats -> bf16 blocked padded interior ----------
__global__ void cast_feat_kernel(const float* __restrict__ in, bf16* __restrict__ out,
                                 int wshift) {
  const int W = 1 << wshift;
  const long PLSZ8 = (long)(W + 2) * (W + 2) * 8;
  const long n4 = 2L * W * W * 64;
  for (long t = blockIdx.x * (long)blockDim.x + threadIdx.x; t < n4;
       t += (long)gridDim.x * blockDim.x) {
    int c4 = (int)(t & 63);
    long q = t >> 6;
    int w = (int)(q & (W - 1));
    long q2 = q >> wshift;
    int h = (int)(q2 & (W - 1));
    int b = (int)(q2 >> wshift);
    const float4 f = *(const float4*)(in + (((long)(b * W + h) * W + w) * 256 + c4 * 4));
    short4v v;
    union { bf16 b16; short s16; } u;
    u.b16 = __float2bfloat16(f.x); v[0] = u.s16;
    u.b16 = __float2bfloat16(f.y); v[1] = u.s16;
    u.b16 = __float2bfloat16(f.z); v[2] = u.s16;
    u.b16 = __float2bfloat16(f.w); v[3] = u.s16;
    *(short4v*)(out + ((long)(b * 32 + (c4 >> 1))) * PLSZ8 +
                ((long)(h + 1) * (W + 2) + (w + 1)) * 8 + (c4 & 1) * 4) = v;
  }
}

// ---------- conv implicit GEMM ----------
// Global activations channel-blocked [img][32 planes of 8ci][pix][8] so the
// A-stage is fully coalesced (round 6's [pix][256] layout made each lane read
// 16B at 512B stride = 64 cache lines per gload_lds). LDS layout and MFMA
// fragment addressing are IDENTICAL to the verified round-6 kernel.

#define MFMA_(a, b, c) __builtin_amdgcn_mfma_f32_32x32x16_bf16((a), (b), (c), 0, 0, 0)

#define STAGE_M(cc, ldsb)                                                        \
  do {                                                                           \
    _Pragma("unroll") for (int i_ = 0; i_ < UPW; ++i_) {                         \
      const int u_ = wid + NW * i_;                                              \
      if (u_ < UA) {                                                             \
        const int cg_ = (u_ >= UAH) ? 1 : 0;                                     \
        const int pu_ = (u_ - cg_ * UAH) * 64;                                   \
        gload16(gA + (long)((cc) * 2 + cg_) * PLSZ8 + (pu_ + lane) * 8,          \
                (ldsb) + (cg_ * PPA + pu_) * 16);                                \
      } else {                                                                   \
        const int s0_ = (u_ - UA) * 64;                                          \
        gload16(gB + (long)(cc) * (TAPS * 2048) + (s0_ + lane) * 8,              \
                (ldsb) + ABYTES + s0_ * 16);                                     \
      }                                                                          \
    }                                                                            \
  } while (0)

#define COMPUTE_M(ldsb)                                                          \
  do {                                                                           \
    _Pragma("unroll") for (int t_ = 0; t_ < TAPS; ++t_) {                        \
      const int TOFF_ = (TAPS == 9) ? ((((t_) / 3) * (W + 2) + ((t_) % 3)) * 16) \
                                    : ((W + 3) * 16);                            \
      const short8 b0_ = *(const short8*)((ldsb) + b16_0 + (t_) * 2048);         \
      const short8 b1_ = *(const short8*)((ldsb) + b16_1 + (t_) * 2048);         \
      {                                                                          \
        const short8 a_ = *(const short8*)((ldsb) + a16_0 + TOFF_);              \
        c0a = MFMA_(a_, b0_, c0a); c0b = MFMA_(a_, b1_, c0b);                    \
      }                                                                          \
      {                                                                          \
        const short8 a_ = *(const short8*)((ldsb) + a16_1 + TOFF_);              \
        c1a = MFMA_(a_, b0_, c1a); c1b = MFMA_(a_, b1_, c1b);                    \
      }                                                                          \
      if constexpr (MFR > 2) {                                                   \
        {                                                                        \
          const short8 a_ = *(const short8*)((ldsb) + a16_2 + TOFF_);            \
          c2a = MFMA_(a_, b0_, c2a); c2b = MFMA_(a_, b1_, c2b);                  \
        }                                                                        \
        {                                                                        \
          const short8 a_ = *(const short8*)((ldsb) + a16_3 + TOFF_);            \
          c3a = MFMA_(a_, b0_, c3a); c3b = MFMA_(a_, b1_, c3b);                  \
        }                                                                        \
      }                                                                          \
    }                                                                            \
  } while (0)

#define AOFF_(mf_)                                                               \
  ((lh * PPA + (((wm * (MFR * 32) + (mf_) * 32 + l31) >> WSH) * (W + 2)) +       \
    ((wm * (MFR * 32) + (mf_) * 32 + l31) & (W - 1))) * 16)

#define STORE_PAIR(mf_, accv, nf_)                                               \
  do {                                                                           \
    const int co_ = n0 + wn * 64 + (nf_) * 32 + l31;                             \
    const float bv_ = bias[co_];                                                 \
    const long pl_ = ((long)(img * 32 + (co_ >> 3))) * PLSZ8 + (co_ & 7);        \
    _Pragma("unroll") for (int r_ = 0; r_ < 16; ++r_) {                          \
      const int mrow_ =                                                          \
          wm * (MFR * 32) + (mf_) * 32 + (r_ & 3) + 8 * (r_ >> 2) + 4 * lh;      \
      const int rr_ = rb * BM + mrow_;                                           \
      const int h_ = rr_ >> WSH;                                                 \
      const int w_ = rr_ & (W - 1);                                              \
      float v_ = accv[r_] + bv_;                                                 \
      if (TAPS == 9) v_ = fmaxf(v_, 0.f);                                        \
      outp[pl_ + ((long)(h_ + 1) * (W + 2) + (w_ + 1)) * 8] =                    \
          __float2bfloat16(v_);                                                  \
    }                                                                            \
  } while (0)

#define LOSS_PAIR(mf_, accv, nf_)                                                \
  do {                                                                           \
    const int co_ = n0 + wn * 64 + (nf_) * 32 + l31;                             \
    if (co_ < Cout) {                                                            \
      const float bv_ = bias[co_];                                               \
      int aidx_, sub_;                                                           \
      if constexpr (EPI == 1) { aidx_ = co_ / 80; sub_ = co_ - aidx_ * 80; }     \
      else { aidx_ = co_ >> 2; sub_ = co_ & 3; }                                 \
      _Pragma("unroll") for (int r_ = 0; r_ < 16; ++r_) {                        \
        const int mrow_ =                                                        \
            wm * (MFR * 32) + (mf_) * 32 + (r_ & 3) + 8 * (r_ >> 2) + 4 * lh;    \
        const int label_ = lsh[mrow_ * 9 + aidx_];                               \
        const float z_ = accv[r_] + bv_;                                         \
        if constexpr (EPI == 1) {                                                \
          if (label_ >= 0) {                                                     \
            const float tt_ = (label_ == sub_) ? 1.f : 0.f;                      \
            const float ce_ = fmaxf(z_, 0.f) - z_ * tt_ + log1pf(expf(-fabsf(z_))); \
            const float p_ = 1.f / (1.f + expf(-z_));                            \
            const float pt_ = p_ * tt_ + (1.f - p_) * (1.f - tt_);               \
            const float om_ = 1.f - pt_;                                         \
            lsum += (0.25f * tt_ + 0.75f * (1.f - tt_)) * ce_ * om_ * om_;       \
          }                                                                      \
        } else {                                                                 \
          if (label_ >= 0 && label_ != 80) {                                     \
            lsum += fabsf(z_ - dsh[(mrow_ * 9 + aidx_) * 4 + sub_]);             \
          }                                                                      \
        }                                                                        \
      }                                                                          \
    }                                                                            \
  } while (0)

template <int WSH, int WM, int WN, int MFR, int TAPS, int EPI>
__global__ __launch_bounds__(WM * WN * 64) void conv_t(
    const bf16* __restrict__ inA, const bf16* __restrict__ inB,
    const bf16* __restrict__ wpA, const bf16* __restrict__ wpB,
    const float* __restrict__ biasA, const float* __restrict__ biasB,
    bf16* __restrict__ outA, bf16* __restrict__ outB,
    const int* __restrict__ labels, const float* __restrict__ tdel,
    int abase, float* __restrict__ lout, int Cout, int nbHalf) {
  constexpr int W = 1 << WSH;
  constexpr int NW = WM * WN;
  constexpr int BM = WM * MFR * 32;
  constexpr int R = BM >> WSH;
  constexpr int PP = (R + 2) * (W + 2);
  constexpr long PLSZ8 = (long)(W + 2) * (W + 2) * 8;
  constexpr int PPA = pick_ppa(PP, TAPS * 4, NW);
  constexpr int UAH = PPA / 64;
  constexpr int UA = PPA / 32;
  constexpr int U = UA + TAPS * 4;
  constexpr int UPW = U / NW;
  constexpr int ABYTES = PPA * 32;
  constexpr int BUFB = ABYTES + TAPS * 4096;

  __shared__ __align__(16) char smem[BUFB * 2];

  const int tid = threadIdx.x;
  const int lane = tid & 63;
  const int wid = tid >> 6;
  const int wm = wid / WN;
  const int wn = wid % WN;
  const int l31 = lane & 31;
  const int lh = lane >> 5;

  const int yb = blockIdx.y;
  const int half = (yb >= nbHalf) ? 1 : 0;
  const int nb = yb - half * nbHalf;
  const int n0 = nb * 128;
  const int rb = blockIdx.x;
  const int img = blockIdx.z;

  const bf16* in = half ? inB : inA;
  const bf16* wp = half ? wpB : wpA;
  const float* bias = half ? biasB : biasA;
  bf16* outp = half ? outB : outA;

  const bf16* gA = in + (long)img * 32 * PLSZ8 + (long)(rb * R) * (W + 2) * 8;
  const bf16* gB = wp + (long)nb * (TAPS * 32768);

  const int a16_0 = AOFF_(0);
  const int a16_1 = AOFF_(1);
  const int a16_2 = (MFR > 2) ? AOFF_(2) : 0;
  const int a16_3 = (MFR > 2) ? AOFF_(3) : 0;
  const int b16_0 = ABYTES + (lh * (TAPS * 128) + wn * 64 + l31) * 16;
  const int b16_1 = ABYTES + (lh * (TAPS * 128) + wn * 64 + 32 + l31) * 16;

  f32x16 c0a = (f32x16)(0.f), c0b = (f32x16)(0.f);
  f32x16 c1a = (f32x16)(0.f), c1b = (f32x16)(0.f);
  f32x16 c2a = (f32x16)(0.f), c2b = (f32x16)(0.f);
  f32x16 c3a = (f32x16)(0.f), c3b = (f32x16)(0.f);

  {
    char* bb0 = smem;
    char* bb1 = smem + BUFB;
    STAGE_M(0, bb0);
#pragma unroll 1
    for (int i = 0; i < 8; ++i) {
      STAGE_M(2 * i + 1, bb1);
      vmw<UPW>();
      __builtin_amdgcn_s_barrier();
      COMPUTE_M(bb0);
      __builtin_amdgcn_s_barrier();
      if (i < 7) {
        STAGE_M(2 * i + 2, bb0);
        vmw<UPW>();
      } else {
        vmw<0>();
      }
      __builtin_amdgcn_s_barrier();
      COMPUTE_M(bb1);
      __builtin_amdgcn_s_barrier();
    }
  }

  if constexpr (EPI == 0) {
    STORE_PAIR(0, c0a, 0); STORE_PAIR(0, c0b, 1);
    STORE_PAIR(1, c1a, 0); STORE_PAIR(1, c1b, 1);
    if constexpr (MFR > 2) {
      STORE_PAIR(2, c2a, 0); STORE_PAIR(2, c2b, 1);
      STORE_PAIR(3, c3a, 0); STORE_PAIR(3, c3b, 1);
    }
  } else {
    __syncthreads();
    int* lsh = (int*)smem;
    float* dsh = (float*)(smem + BM * 9 * 4);
    const long lbase = (long)img * NT + abase + (long)rb * BM * 9;
    for (int i = tid; i < BM * 9; i += NW * 64) lsh[i] = labels[lbase + i];
    if constexpr (EPI == 2) {
      for (int i = tid; i < BM * 9 * 4; i += NW * 64) dsh[i] = tdel[lbase * 4 + i];
    }
    __syncthreads();

    float lsum = 0.f;
    LOSS_PAIR(0, c0a, 0); LOSS_PAIR(0, c0b, 1);
    LOSS_PAIR(1, c1a, 0); LOSS_PAIR(1, c1b, 1);
    if constexpr (MFR > 2) {
      LOSS_PAIR(2, c2a, 0); LOSS_PAIR(2, c2b, 1);
      LOSS_PAIR(3, c3a, 0); LOSS_PAIR(3, c3b, 1);
    }
#pragma unroll
    for (int off = 32; off > 0; off >>= 1) lsum += __shfl_down(lsum, off, 64);
    __syncthreads();
    float* red = (float*)smem;
    if (lane == 0) red[wid] = lsum;
    __syncthreads();
    if (tid == 0) {
      float s = 0.f;
      for (int i = 0; i < NW; ++i) s += red[i];
      atomicAdd(lout, s * 0.01f);
    }
  }
}

// ---------------- host ----------------
static inline int igrid(long n, int cap) {
  long g = (n + 255) / 256;
  return (int)(g > cap ? cap : g);
}

struct LvlArgs {
  bf16* bufs; long BS;
  const bf16 *wip, *wcls, *wbox, *wsc, *wpred;
  const float *ipb, *ccb, *csb, *bcb, *bpb;
  const int* labels; const float* tdel;
  int abase; float* out;
};

template <int WSH, int WM, int WN, int MFR>
static void run_level(const LvlArgs& A, bool merged, hipStream_t s) {
  constexpr int W = 1 << WSH;
  constexpr int BM = WM * MFR * 32;
  const int m = (W * W) / BM;
  dim3 blk(WM * WN * 64);
  if (merged) {
    bf16* xb = A.bufs;
    bf16* c0 = A.bufs + A.BS;
    bf16* c1 = A.bufs + 2 * A.BS;
    bf16* d0 = A.bufs + 3 * A.BS;
    bf16* d1 = A.bufs + 4 * A.BS;
    conv_t<WSH, WM, WN, MFR, 1, 0><<<dim3(m, 2, 2), blk, 0, s>>>(
        c1, c1, A.wip, A.wip, A.ipb, A.ipb, xb, xb, nullptr, nullptr, 0, nullptr, 256, 2);
    const bf16* ci = xb; const bf16* bi = xb;
    bf16* co_[4] = {c0, c1, c0, c1};
    bf16* bo_[4] = {d0, d1, d0, d1};
    for (int j = 0; j < 4; ++j) {
      conv_t<WSH, WM, WN, MFR, 9, 0><<<dim3(m, 4, 2), blk, 0, s>>>(
          ci, bi, A.wcls + (long)j * 589824, A.wbox + (long)j * 589824,
          A.ccb + j * 256, A.bcb + j * 256, co_[j], bo_[j],
          nullptr, nullptr, 0, nullptr, 256, 2);
      ci = co_[j]; bi = bo_[j];
    }
    conv_t<WSH, WM, WN, MFR, 9, 1><<<dim3(m, 6, 2), blk, 0, s>>>(
        ci, ci, A.wsc, A.wsc, A.csb, A.csb, nullptr, nullptr,
        A.labels, nullptr, A.abase, A.out + 0, 720, 6);
    conv_t<WSH, WM, WN, MFR, 9, 2><<<dim3(m, 1, 2), blk, 0, s>>>(
        bi, bi, A.wpred, A.wpred, A.bpb, A.bpb, nullptr, nullptr,
        A.labels, A.tdel, A.abase, A.out + 1, 36, 1);
  } else {
    bf16* xb = A.bufs;
    bf16* t0 = A.bufs + A.BS;
    bf16* t1 = A.bufs + 2 * A.BS;
    conv_t<WSH, WM, WN, MFR, 1, 0><<<dim3(m, 2, 2), blk, 0, s>>>(
        t0, t0, A.wip, A.wip, A.ipb, A.ipb, xb, xb, nullptr, nullptr, 0, nullptr, 256, 2);
    for (int br = 0; br < 2; ++br) {
      const bf16* wt = br ? A.wbox : A.wcls;
      const float* bb = br ? A.bcb : A.ccb;
      const bf16* ci = xb;
      bf16* oo[4] = {t1, t0, t1, t0};
      for (int j = 0; j < 4; ++j) {
        conv_t<WSH, WM, WN, MFR, 9, 0><<<dim3(m, 2, 2), blk, 0, s>>>(
            ci, ci, wt + (long)j * 589824, wt + (long)j * 589824, bb + j * 256, bb + j * 256,
            oo[j], oo[j], nullptr, nullptr, 0, nullptr, 256, 2);
        ci = oo[j];
      }
      if (br == 0)
        conv_t<WSH, WM, WN, MFR, 9, 1><<<dim3(m, 6, 2), blk, 0, s>>>(
            t0, t0, A.wsc, A.wsc, A.csb, A.csb, nullptr, nullptr,
            A.labels, nullptr, A.abase, A.out + 0, 720, 6);
      else
        conv_t<WSH, WM, WN, MFR, 9, 2><<<dim3(m, 1, 2), blk, 0, s>>>(
            t0, t0, A.wpred, A.wpred, A.bpb, A.bpb, nullptr, nullptr,
            A.labels, A.tdel, A.abase, A.out + 1, 36, 1);
    }
  }
}

extern "C" void kernel_launch(void* const* d_in, const int* in_sizes, int n_in,
                              void* d_out, int out_size, void* d_ws, size_t ws_size,
                              hipStream_t stream) {
  const float* feat_in[5] = {(const float*)d_in[0], (const float*)d_in[1],
                             (const float*)d_in[2], (const float*)d_in[3],
                             (const float*)d_in[4]};
  const int* labels = (const int*)d_in[5];
  const float* adeltas = (const float*)d_in[6];
  const float* ipw = (const float*)d_in[7];
  const float* ipb = (const float*)d_in[8];
  const float* ccw = (const float*)d_in[9];
  const float* ccb = (const float*)d_in[10];
  const float* csw = (const float*)d_in[11];
  const float* csb = (const float*)d_in[12];
  const float* bcw = (const float*)d_in[13];
  const float* bcb = (const float*)d_in[14];
  const float* bpw = (const float*)d_in[15];
  const float* bpb = (const float*)d_in[16];
  float* out = (float*)d_out;

  const long BUFE = 2L * 130 * 130 * 256;
  const long GAP = 65536;
  const long BS = BUFE + GAP;
  const long WELEMS = 327680 + 2359296 + 2359296 + 1769472 + 294912;
  const bool merged = ws_size >= (size_t)((5 * BS + WELEMS) * 2);
  const int nbuf = merged ? 5 : 3;

  bf16* ws = (bf16*)d_ws;
  bf16* wp_ip = ws + nbuf * BS;
  bf16* wp_cls = wp_ip + 327680;
  bf16* wp_box = wp_cls + 2359296;
  bf16* wp_sc = wp_box + 2359296;
  bf16* wp_pred = wp_sc + 1769472;

  hipMemsetAsync(d_out, 0, 2 * sizeof(float), stream);

  prep_w<<<igrid(5L * 8192, 1024), 256, 0, stream>>>(ipw, wp_ip, 256, 2, 1, 5, 65536);
  prep_w<<<igrid(4L * 73728, 1024), 256, 0, stream>>>(ccw, wp_cls, 256, 2, 9, 4, 589824);
  prep_w<<<igrid(4L * 73728, 1024), 256, 0, stream>>>(bcw, wp_box, 256, 2, 9, 4, 589824);
  prep_w<<<igrid(221184L, 1024), 256, 0, stream>>>(csw, wp_sc, 720, 6, 9, 1, 0);
  prep_w<<<igrid(36864L, 1024), 256, 0, stream>>>(bpw, wp_pred, 36, 1, 9, 1, 0);

  static const int LS[5] = {7, 6, 5, 4, 3};
  static const int AB[5] = {0, 147456, 184320, 193536, 195840};

  bf16* featsBuf = ws + (merged ? 2 : 1) * BS;

  for (int l = 0; l < 5; ++l) {
    const int W = 1 << LS[l];
    halo_kernel<<<igrid((long)nbuf * 2 * (4 * W + 4) * 256, 2048), 256, 0, stream>>>(
        ws, BS, W, nbuf);
    cast_feat_kernel<<<igrid(2L * W * W * 64, 2048), 256, 0, stream>>>(
        feat_in[l], featsBuf, LS[l]);

    LvlArgs A;
    A.bufs = ws; A.BS = BS;
    A.wip = wp_ip + (long)l * 65536; A.ipb = ipb + l * 256;
    A.wcls = wp_cls; A.wbox = wp_box; A.wsc = wp_sc; A.wpred = wp_pred;
    A.ccb = ccb; A.csb = csb; A.bcb = bcb; A.bpb = bpb;
    A.labels = labels; A.tdel = adeltas; A.abase = AB[l]; A.out = out;

    switch (l) {
      case 0: run_level<7, 4, 2, 4>(A, merged, stream); break;
      case 1: run_level<6, 2, 2, 2>(A, merged, stream); break;
      case 2: run_level<5, 1, 2, 2>(A, merged, stream); break;
      case 3: run_level<4, 1, 2, 2>(A, merged, stream); break;
      case 4: run_level<3, 1, 2, 2>(A, merged, stream); break;
    }
  }
}